// Round 8
// baseline (1443.201 us; speedup 1.0000x reference)
//
#include <hip/hip_runtime.h>
#include <cstdint>
#include <cstddef>

// SimpleRNN: B=4096, K=512, U=3, P=5, LIFT=32, HID=128, NSUB=10
// Round 11: resubmission of round-10 (infra failure, no perf signal).
// 3 phases -> 2. The serial loop y->lift->gates->head->theta->rk4->y
// previously crossed 3 barriers and an LDS round trip (yst). Now:
//  - y lives in wave0 REGISTERS across all 512 steps (never in LDS).
//  - lift u-part (au = bl + W_u u) computed by all threads during GATE (y-free);
//    wave0 adds the y-part via quad-DPP broadcasts right after RK4 and writes
//    xls itself -> LIFT phase + its barrier deleted.
//  - ust/dtst triple-buffered (prefetch k+2 in CD(k)): au(k+1) written GATE(k),
//    read by wave0 in CD(k) one barrier later; u(k) jump read in CD(k) from a
//    slot not overwritten until CD(k+1).
//  - head MFMA chain split 4 -> 2+2 (+vector add).
// Output ring (round 6) kept: flush every 16 steps by waves 1-7, coalesced.

#define KTOT 512
#define BB   16

typedef _Float16 half8 __attribute__((ext_vector_type(8)));
typedef float    f32x4 __attribute__((ext_vector_type(4)));

struct __align__(16) Smem {
  _Float16 hf16[BB][136];        // f16 hidden (A-frag source)       4352 B
  _Float16 xls[BB][32];          // f16 lift output (A-frag source)  1024 B
  float au[BB][32];              // lift u-part for step k+1         2048 B
  float yring[2][BB][16][5];     // output ring                     10240 B
  float thring[2][BB][16][13];   // theta ring (+ RK4 transpose)    26624 B
  float brz[256];
  float bnx[128];
  float bnh[128];
  float bhv[16];
  float ust[3][BB][4];           // triple-buffered u
  float dtst[3][BB];             // triple-buffered dt
};

__device__ __forceinline__ float sigm(float x)     { return 1.f / (1.f + __expf(-x)); }
__device__ __forceinline__ float tanhfast(float x) { return 1.f - 2.f / (1.f + __expf(2.f * x)); }

template<int CTRL>
__device__ __forceinline__ float dppf(float x) {
  return __int_as_float(__builtin_amdgcn_mov_dpp(__float_as_int(x), CTRL, 0xf, 0xf, true));
}
#define QP_PLUS  0x39   // quad_perm [1,2,3,0]
#define QP_MINUS 0x93   // quad_perm [3,0,1,2]
#define QB0 0x00
#define QB1 0x55
#define QB2 0xAA
#define QB3 0xFF

// Y = I + ALPHA * Z * X   (row-per-lane; lane3 also owns row4 in X4r/Y4r)
#define MATMUL(Yr, Y4r, Xr, X4r, ALPHA) do {                                  \
  float xm_[5], xp_[5];                                                       \
  _Pragma("unroll")                                                           \
  for (int j_ = 0; j_ < 5; j_++) {                                            \
    xm_[j_] = dppf<QP_MINUS>(Xr[j_]);                                         \
    xp_[j_] = dppf<QP_PLUS >(Xr[j_]);                                         \
  }                                                                           \
  _Pragma("unroll")                                                           \
  for (int j_ = 0; j_ < 5; j_++) {                                            \
    const float ac_ = Zl*xm_[j_] + Zd*Xr[j_] + Zu*xp_[j_] + Zu4*X4r[j_];      \
    const float a4_ = Z43*Xr[j_] + Z44*X4r[j_];                               \
    Yr[j_]  = ((j_ == s_) ? 1.f : 0.f) + (ALPHA)*ac_;                         \
    Y4r[j_] = ((j_ == 4 ) ? 1.f : 0.f) + (ALPHA)*a4_;                         \
  } } while (0)

__global__ __launch_bounds__(512, 2) void rnn_scan_kernel(
    const float* __restrict__ y0,    const float* __restrict__ u_seq,
    const float* __restrict__ dt_sq, const float* __restrict__ Wl,
    const float* __restrict__ bl,    const float* __restrict__ W_ih,
    const float* __restrict__ b_ih,  const float* __restrict__ W_hh,
    const float* __restrict__ b_hh,  const float* __restrict__ Wh,
    const float* __restrict__ bh,    const float* __restrict__ jmp,
    float* __restrict__ y_out, float* __restrict__ th_out)
{
  __shared__ Smem sm;
  const int t   = threadIdx.x;
  const int w   = t >> 6;          // 0..7
  const int l   = t & 63;
  const int n16 = l & 15;
  const int q   = l >> 4;
  const int B0  = blockIdx.x * BB;

  // ---------------- one-time init: stage 1 (global -> LDS) ----------------
  if (t < 256) sm.brz[t] = b_ih[t] + b_hh[t];
  if (t < 128) { sm.bnx[t] = b_ih[256+t]; sm.bnh[t] = b_hh[256+t]; }
  if (t < 16)  sm.bhv[t] = (t < 13) ? bh[t] : 0.f;
  if (t >= 256 && t < 336) { const int b = (t-256)/5, i = (t-256) - ((t-256)/5)*5;
    sm.yring[0][b][0][i] = y0[(size_t)(B0+b)*5 + i] + 0.01f; }   // init-y scratch
  if (t >= 384 && t < 480) { const int idx = t-384, st = idx/48;
    const int r = idx - st*48, b = r/3, c = r - (r/3)*3;
    sm.ust[st][b][c] = u_seq[((size_t)(B0+b)*KTOT + st)*3 + c]; }
  if (t >= 480) { const int idx = t-480, st = idx >> 4, b = idx & 15;
    sm.dtst[st][b] = dt_sq[(size_t)(B0+b)*KTOT + st]; }

  // lift weights: full column per thread (init xls + au); y-columns for wave0 lift
  const int lb = t >> 5;           // batch 0..15
  const int lo = t & 31;           // lift out col 0..31
  float wlc[8];
  #pragma unroll
  for (int c = 0; c < 8; c++) wlc[c] = Wl[lo*8 + c];
  const float blv = bl[lo];

  // RK4 lane mapping (wave0): lane = b4*4 + s_
  const int s_ = l & 3, b4 = l >> 2;
  float wlyv[5][8];                // Wl y-part columns for this lane's 8 lift outputs
  #pragma unroll
  for (int j = 0; j < 5; j++)
    #pragma unroll
    for (int i = 0; i < 8; i++) wlyv[j][i] = Wl[(s_*8 + i)*8 + 3 + j];
  const float jr0 = jmp[0*5 + s_], jr1 = jmp[1*5 + s_], jr2 = jmp[2*5 + s_];
  const float j40 = (s_==3) ? jmp[4]  : 0.f;
  const float j41 = (s_==3) ? jmp[9]  : 0.f;
  const float j42 = (s_==3) ? jmp[14] : 0.f;

  // wave0 y state in registers (carried across all K steps)
  float y  = y0[(size_t)(B0+b4)*5 + s_] + 0.01f;
  float y4 = (s_==3) ? (y0[(size_t)(B0+b4)*5 + 4] + 0.01f) : 0.f;

  // head B-frags (wave0 use)
  half8 whf[4];
  #pragma unroll
  for (int ks = 0; ks < 4; ks++)
    #pragma unroll
    for (int i = 0; i < 8; i++) {
      const int kk = ks*32 + q*8 + i;
      whf[ks][i] = (n16 < 13) ? (_Float16)Wh[n16*128 + kk] : (_Float16)0.f;
    }

  // GRU weight fragments: this wave's single 16-col slice
  const int jR = w*16 + n16;
  const int jZ = jR + 128, jN = jR + 256;
  half8 wihR, wihZ, wihN, whhR[4], whhZ[4], whhN[4];
  #pragma unroll
  for (int i = 0; i < 8; i++) {
    const int kk = q*8 + i;
    wihR[i] = (_Float16)W_ih[jR*32 + kk];
    wihZ[i] = (_Float16)W_ih[jZ*32 + kk];
    wihN[i] = (_Float16)W_ih[jN*32 + kk];
  }
  #pragma unroll
  for (int ks = 0; ks < 4; ks++)
    #pragma unroll
    for (int i = 0; i < 8; i++) {
      const int kk = ks*32 + q*8 + i;
      whhR[ks][i] = (_Float16)W_hh[jR*128 + kk];
      whhZ[ks][i] = (_Float16)W_hh[jZ*128 + kk];
      whhN[ks][i] = (_Float16)W_hh[jN*128 + kk];
    }

  float hreg[4] = {0.f, 0.f, 0.f, 0.f};
  const f32x4 zero4 = {0.f, 0.f, 0.f, 0.f};
  f32x4 accPreR = zero4, accPreZ = zero4, accPreN = zero4;

  // u-prefetch mapping (wave1)
  const int upb = l/3, upc = l - (l/3)*3;             // l < 48

  __syncthreads();

  // ---------------- init stage 2: x(0) + bias hoist ----------------
  {
    const f32x4 uu = *(const f32x4*)&sm.ust[0][lb][0];
    const f32x4 ya = *(const f32x4*)&sm.yring[0][lb][0][0];
    const float y4i = sm.yring[0][lb][0][4];
    const float a = blv
      + uu[0]*wlc[0] + uu[1]*wlc[1] + uu[2]*wlc[2]
      + ya[0]*wlc[3] + ya[1]*wlc[4] + ya[2]*wlc[5] + ya[3]*wlc[6]
      + y4i*wlc[7];
    sm.xls[lb][lo] = (_Float16)(a * sigm(a));
  }
  const float br  = sm.brz[jR];
  const float bz  = sm.brz[128 + jR];
  const float bx  = sm.bnx[jR];
  const float bn  = sm.bnh[jR];
  const float bb_ = sm.bhv[n16];
  __syncthreads();

  #pragma unroll 1
  for (int k = 0; k < KTOT; k++) {
    const int kp2 = (k + 2 < KTOT) ? (k + 2) : (KTOT - 1);

    // ---- phase GATE: x-part MFMAs + activations; au(k+1) ----
    {
      const half8 xf = *(const half8*)&sm.xls[n16][q*8];
      const f32x4 accR  = __builtin_amdgcn_mfma_f32_16x16x32_f16(xf, wihR, accPreR, 0,0,0);
      const f32x4 accZ  = __builtin_amdgcn_mfma_f32_16x16x32_f16(xf, wihZ, accPreZ, 0,0,0);
      const f32x4 accXN = __builtin_amdgcn_mfma_f32_16x16x32_f16(xf, wihN, zero4,   0,0,0);
      // au for step k+1 (u-part of lift; y-free, off critical path)
      {
        const f32x4 uu = *(const f32x4*)&sm.ust[(k+1)%3][lb][0];
        sm.au[lb][lo] = blv + uu[0]*wlc[0] + uu[1]*wlc[1] + uu[2]*wlc[2];
      }
      #pragma unroll
      for (int rg = 0; rg < 4; rg++) {
        const float r  = sigm(accR[rg] + br);
        const float z  = sigm(accZ[rg] + bz);
        const float nn = tanhfast(accXN[rg] + bx + r*(accPreN[rg] + bn));
        const float ho = hreg[rg];
        const float hn = nn + z*(ho - nn);
        hreg[rg] = hn;
        sm.hf16[q*4 + rg][jR] = (_Float16)hn;
      }
    }
    __syncthreads();

    // ---- phase CD: h-GEMM(k+1) || wave0: head+theta+RK4+lift || w1-7: flush ----
    float pref_u = 0.f, pref_dt = 0.f;
    if (w == 1 && l < 48)
      pref_u = u_seq[((size_t)(B0 + upb)*KTOT + kp2)*3 + upc];
    if (w == 2 && l < 16)
      pref_dt = dt_sq[(size_t)(B0 + l)*KTOT + kp2];

    half8 hfrag[4];
    #pragma unroll
    for (int ks = 0; ks < 4; ks++)
      hfrag[ks] = *(const half8*)&sm.hf16[n16][ks*32 + q*8];

    accPreR = zero4; accPreZ = zero4; accPreN = zero4;
    #pragma unroll
    for (int ks = 0; ks < 4; ks++) {
      accPreR = __builtin_amdgcn_mfma_f32_16x16x32_f16(hfrag[ks], whhR[ks], accPreR, 0,0,0);
      accPreZ = __builtin_amdgcn_mfma_f32_16x16x32_f16(hfrag[ks], whhZ[ks], accPreZ, 0,0,0);
      accPreN = __builtin_amdgcn_mfma_f32_16x16x32_f16(hfrag[ks], whhN[ks], accPreN, 0,0,0);
    }

    if (w == 0) {
      const int km = k & 15, hh = (k >> 4) & 1;
      // lift u-part loads issued early (consumed at the end of the tail)
      const f32x4 au0 = *(const f32x4*)&sm.au[b4][s_*8];
      const f32x4 au1 = *(const f32x4*)&sm.au[b4][s_*8 + 4];
      // head -> theta (two 2-deep MFMA chains)
      f32x4 accHa = __builtin_amdgcn_mfma_f32_16x16x32_f16(hfrag[0], whf[0], zero4, 0,0,0);
      f32x4 accHb = __builtin_amdgcn_mfma_f32_16x16x32_f16(hfrag[2], whf[2], zero4, 0,0,0);
      accHa = __builtin_amdgcn_mfma_f32_16x16x32_f16(hfrag[1], whf[1], accHa, 0,0,0);
      accHb = __builtin_amdgcn_mfma_f32_16x16x32_f16(hfrag[3], whf[3], accHb, 0,0,0);
      const f32x4 accH = accHa + accHb;
      #pragma unroll
      for (int rg = 0; rg < 4; rg++) {
        const float sg  = sigm(accH[rg] + bb_);
        const float thv = (n16 < 8) ? (0.01f + 2.99f*sg) : (0.3f*sg);
        if (n16 < 13) sm.thring[hh][q*4 + rg][km][n16] = thv;
      }
      // ---- exact-linear RK4 (LDS ops in-order within wave) ----
      const float* th = &sm.thring[hh][b4][km][0];
      const float dt = sm.dtst[k%3][b4];
      const float h  = dt * 0.1f;
      const float thm = th[s_ ? (s_ - 1) : 0];
      const float Zl  = s_ ? h*thm : 0.f;
      const float krs = s_ ? th[3 + s_] : 0.f;
      const float Zd  = -h*(th[s_] + krs);
      const float Zur = h*th[4 + s_];
      const float Zu  = (s_ < 3) ? Zur : 0.f;
      const float Zu4 = (s_ == 3) ? Zur : 0.f;
      const float Z43 = h*th[3];
      const float Z44 = -h*th[7];
      const float c0 = th[8], c1 = th[9], c2 = th[10], c3 = th[11], c4 = th[12];
      float Xa[5], Xa4[5], Xb[5], Xb4[5];
      #pragma unroll
      for (int j = 0; j < 5; j++) {
        const float zr = (j == s_) ? Zd : ((j == s_ + 1) ? Zur : ((j + 1 == s_) ? Zl : 0.f));
        Xa[j] = ((j == s_) ? 1.f : 0.f) + 0.25f*zr;
      }
      Xa4[0] = 0.f; Xa4[1] = 0.f; Xa4[2] = 0.f;
      Xa4[3] = 0.25f*Z43; Xa4[4] = 1.f + 0.25f*Z44;
      MATMUL(Xb, Xb4, Xa, Xa4, (1.f/3.f));   // X2 = I + (Z/3) X1
      MATMUL(Xa, Xa4, Xb, Xb4, 0.5f);        // X3 = S = I + (Z/2) X2
      const float bv  = h*(Xa[0]*c0 + Xa[1]*c1 + Xa[2]*c2 + Xa[3]*c3 + Xa[4]*c4);
      const float bv4 = h*(Xa4[0]*c0 + Xa4[1]*c1 + Xa4[2]*c2 + Xa4[3]*c3 + Xa4[4]*c4);
      MATMUL(Xb, Xb4, Xa, Xa4, 1.f);         // A = I + Z S
      const float uu0 = sm.ust[k%3][b4][0], uu1 = sm.ust[k%3][b4][1], uu2 = sm.ust[k%3][b4][2];
      y  += uu0*jr0 + uu1*jr1 + uu2*jr2;
      y4 += uu0*j40 + uu1*j41 + uu2*j42;
      #pragma unroll
      for (int ss = 0; ss < 10; ss++) {
        const float v0 = dppf<QB0>(y), v1 = dppf<QB1>(y),
                    v2 = dppf<QB2>(y), v3 = dppf<QB3>(y);
        const float v4 = dppf<QB3>(y4);
        const float a1 = fmaf(Xb[0],  v0, bv);
        const float a2 = fmaf(Xb[2],  v2, Xb[1]*v1);
        const float a3 = fmaf(Xb[4],  v4, Xb[3]*v3);
        const float b1 = fmaf(Xb4[0], v0, bv4);
        const float b2 = fmaf(Xb4[2], v2, Xb4[1]*v1);
        const float b3 = fmaf(Xb4[4], v4, Xb4[3]*v3);
        y  = fmaxf(a1 + (a2 + a3), 0.f);
        y4 = fmaxf(b1 + (b2 + b3), 0.f);
      }
      sm.yring[hh][b4][km][s_] = y;
      if (s_ == 3) sm.yring[hh][b4][km][4] = y4;
      // ---- lift for step k+1: y-part in-register via quad DPP ----
      {
        const float v0 = dppf<QB0>(y), v1 = dppf<QB1>(y),
                    v2 = dppf<QB2>(y), v3 = dppf<QB3>(y);
        const float v4 = dppf<QB3>(y4);
        half8 xv;
        #pragma unroll
        for (int i = 0; i < 8; i++) {
          const float aui = (i < 4) ? au0[i] : au1[i-4];
          const float a = aui + v0*wlyv[0][i] + v1*wlyv[1][i] + v2*wlyv[2][i]
                              + v3*wlyv[3][i] + v4*wlyv[4][i];
          xv[i] = (_Float16)(a * sigm(a));
        }
        *(half8*)&sm.xls[b4][s_*8] = xv;
      }
    } else {
      // ---- ring flush: steps k-16..k-1, coalesced f32x4, waves 1-7 only ----
      if ((k & 15) == 0 && k >= 16) {
        const int hf = ((k >> 4) & 1) ^ 1;
        const int kb = k - 16;
        const int idx = t - 64;                  // 0..447
        #pragma unroll
        for (int rep = 0; rep < 3; rep++) {
          const int o = idx + rep*448;
          if (o < 1152) {
            if (o < 320) {
              const int b = o/20, j = o - (o/20)*20;
              *(f32x4*)&y_out[((size_t)(B0 + b)*KTOT + kb)*5 + j*4] =
                  *(const f32x4*)((const float*)&sm.yring[hf][b][0][0] + j*4);
            } else {
              const int o2 = o - 320;
              const int b = o2/52, j = o2 - (o2/52)*52;
              *(f32x4*)&th_out[((size_t)(B0 + b)*KTOT + kb)*13 + j*4] =
                  *(const f32x4*)((const float*)&sm.thring[hf][b][0][0] + j*4);
            }
          }
        }
      }
    }
    // land prefetch (k+2) into LDS
    if (w == 1 && l < 48) sm.ust[(k+2)%3][upb][upc] = pref_u;
    if (w == 2 && l < 16) sm.dtst[(k+2)%3][l] = pref_dt;
    __syncthreads();
  }

  // epilogue: flush the last 16 steps (steps 496..511, half index 1)
  {
    const int kb = KTOT - 16;
    const int hf = 1;
    #pragma unroll
    for (int rep = 0; rep < 3; rep++) {
      const int o = t + rep*512;
      if (o < 1152) {
        if (o < 320) {
          const int b = o/20, j = o - (o/20)*20;
          *(f32x4*)&y_out[((size_t)(B0 + b)*KTOT + kb)*5 + j*4] =
              *(const f32x4*)((const float*)&sm.yring[hf][b][0][0] + j*4);
        } else {
          const int o2 = o - 320;
          const int b = o2/52, j = o2 - (o2/52)*52;
          *(f32x4*)&th_out[((size_t)(B0 + b)*KTOT + kb)*13 + j*4] =
              *(const f32x4*)((const float*)&sm.thring[hf][b][0][0] + j*4);
        }
      }
    }
  }
}

extern "C" void kernel_launch(void* const* d_in, const int* in_sizes, int n_in,
                              void* d_out, int out_size, void* d_ws, size_t ws_size,
                              hipStream_t stream) {
  const float* y0     = (const float*)d_in[0];
  const float* u_seq  = (const float*)d_in[1];
  const float* dt_sq  = (const float*)d_in[2];
  const float* Wl     = (const float*)d_in[3];
  const float* bl     = (const float*)d_in[4];
  const float* W_ih   = (const float*)d_in[5];
  const float* b_ih   = (const float*)d_in[6];
  const float* W_hh   = (const float*)d_in[7];
  const float* b_hh   = (const float*)d_in[8];
  const float* Wh     = (const float*)d_in[9];
  const float* bh     = (const float*)d_in[10];
  const float* jmp    = (const float*)d_in[11];
  float* y_out  = (float*)d_out;
  float* th_out = y_out + (size_t)4096 * KTOT * 5;   // y (B,K,5) then theta (B,K,13)
  rnn_scan_kernel<<<256, 512, 0, stream>>>(
      y0, u_seq, dt_sq, Wl, bl, W_ih, b_ih, W_hh, b_hh, Wh, bh, jmp, y_out, th_out);
}

// Round 9
// 1426.373 us; speedup vs baseline: 1.0118x; 1.0118x over previous
//
#include <hip/hip_runtime.h>
#include <cstdint>
#include <cstddef>

// SimpleRNN: B=4096, K=512, U=3, P=5, LIFT=32, HID=128, NSUB=10
// Round 12: base = round 6 (1310 us, best). Round 8 proved the critical
// resource is the single-wave serial CD tail (head->theta->RK4). This round:
//  - Tail SPLIT across waves 0 (batches 0-7) and 1 (batches 8-15), which land
//    on different SIMDs: per-tail-wave issue halves, halves run concurrently.
//    Head MFMA computed redundantly in both (2 extra MFMAs, free).
//  - Tail reordered: head+sigm+thring-write FIRST, then the 12 h-GEMM MFMAs
//    (result not needed until next GATE) fill the thring write->read LDS gap,
//    then RK4.
//  - s_setprio(1) on tail waves (T5: wave role-split -> arbitration pays).
//  - u/dt prefetch -> waves 2/3; ring flush -> waves 4-7 (5 reps x 256).
// Everything else identical to round 6 (3-phase, yst in LDS, ring outputs).

#define KTOT 512
#define BB   16

typedef _Float16 half8 __attribute__((ext_vector_type(8)));
typedef float    f32x4 __attribute__((ext_vector_type(4)));

struct __align__(16) Smem {
  _Float16 hf16[BB][136];        // f16 hidden (A-frag source)       4352 B
  _Float16 xls[BB][32];          // f16 lift output (A-frag source)  1024 B
  float yring[2][BB][16][5];     // output ring                     10240 B
  float thring[2][BB][16][13];   // theta ring (+ RK4 transpose)    26624 B
  float brz[256];
  float bnx[128];
  float bnh[128];
  float bhv[16];
  float yst[BB][8];
  float ust[2][BB][4];           // double-buffered u
  float dtst[2][BB];             // double-buffered dt
};

__device__ __forceinline__ float sigm(float x)     { return 1.f / (1.f + __expf(-x)); }
__device__ __forceinline__ float tanhfast(float x) { return 1.f - 2.f / (1.f + __expf(2.f * x)); }

template<int CTRL>
__device__ __forceinline__ float dppf(float x) {
  return __int_as_float(__builtin_amdgcn_mov_dpp(__float_as_int(x), CTRL, 0xf, 0xf, true));
}
#define QP_PLUS  0x39   // quad_perm [1,2,3,0]
#define QP_MINUS 0x93   // quad_perm [3,0,1,2]
#define QB0 0x00
#define QB1 0x55
#define QB2 0xAA
#define QB3 0xFF

// Y = I + ALPHA * Z * X   (row-per-lane; lane3 also owns row4 in X4r/Y4r)
#define MATMUL(Yr, Y4r, Xr, X4r, ALPHA) do {                                  \
  float xm_[5], xp_[5];                                                       \
  _Pragma("unroll")                                                           \
  for (int j_ = 0; j_ < 5; j_++) {                                            \
    xm_[j_] = dppf<QP_MINUS>(Xr[j_]);                                         \
    xp_[j_] = dppf<QP_PLUS >(Xr[j_]);                                         \
  }                                                                           \
  _Pragma("unroll")                                                           \
  for (int j_ = 0; j_ < 5; j_++) {                                            \
    const float ac_ = Zl*xm_[j_] + Zd*Xr[j_] + Zu*xp_[j_] + Zu4*X4r[j_];      \
    const float a4_ = Z43*Xr[j_] + Z44*X4r[j_];                               \
    Yr[j_]  = ((j_ == s_) ? 1.f : 0.f) + (ALPHA)*ac_;                         \
    Y4r[j_] = ((j_ == 4 ) ? 1.f : 0.f) + (ALPHA)*a4_;                         \
  } } while (0)

__global__ __launch_bounds__(512, 2) void rnn_scan_kernel(
    const float* __restrict__ y0,    const float* __restrict__ u_seq,
    const float* __restrict__ dt_sq, const float* __restrict__ Wl,
    const float* __restrict__ bl,    const float* __restrict__ W_ih,
    const float* __restrict__ b_ih,  const float* __restrict__ W_hh,
    const float* __restrict__ b_hh,  const float* __restrict__ Wh,
    const float* __restrict__ bh,    const float* __restrict__ jmp,
    float* __restrict__ y_out, float* __restrict__ th_out)
{
  __shared__ Smem sm;
  const int t   = threadIdx.x;
  const int w   = t >> 6;          // 0..7
  const int l   = t & 63;
  const int n16 = l & 15;
  const int q   = l >> 4;
  const int B0  = blockIdx.x * BB;

  // ---------------- one-time init ----------------
  if (t < 256) sm.brz[t] = b_ih[t] + b_hh[t];
  if (t < 128) { sm.bnx[t] = b_ih[256+t]; sm.bnh[t] = b_hh[256+t]; }
  if (t < 16)  sm.bhv[t] = (t < 13) ? bh[t] : 0.f;
  if (t >= 256 && t < 384) { const int b = (t-256) >> 3, i = (t-256) & 7;
    sm.yst[b][i] = (i < 5) ? (y0[(size_t)(B0+b)*5 + i] + 0.01f) : 0.f; }
  if (t >= 384 && t < 432) { const int idx = t-384, b = idx/3, c = idx - (idx/3)*3;
    sm.ust[0][b][c] = u_seq[((size_t)(B0+b)*KTOT + 0)*3 + c]; }
  if (t >= 432 && t < 448) sm.dtst[0][t-432] = dt_sq[(size_t)(B0+(t-432))*KTOT + 0];

  // lift: one output per thread; Wl column pinned in VGPRs (loop-invariant)
  const int lb = t >> 5;           // batch 0..15
  const int lo = t & 31;           // lift out col 0..31
  float wlc[8];
  #pragma unroll
  for (int c = 0; c < 8; c++) wlc[c] = Wl[lo*8 + c];
  const float blv = bl[lo];

  // head B-frags (tail waves use; loaded by all, cheap)
  half8 whf[4];
  #pragma unroll
  for (int ks = 0; ks < 4; ks++)
    #pragma unroll
    for (int i = 0; i < 8; i++) {
      const int kk = ks*32 + q*8 + i;
      whf[ks][i] = (n16 < 13) ? (_Float16)Wh[n16*128 + kk] : (_Float16)0.f;
    }

  // GRU weight fragments: this wave's single 16-col slice
  const int jR = w*16 + n16;
  const int jZ = jR + 128, jN = jR + 256;
  half8 wihR, wihZ, wihN, whhR[4], whhZ[4], whhN[4];
  #pragma unroll
  for (int i = 0; i < 8; i++) {
    const int kk = q*8 + i;
    wihR[i] = (_Float16)W_ih[jR*32 + kk];
    wihZ[i] = (_Float16)W_ih[jZ*32 + kk];
    wihN[i] = (_Float16)W_ih[jN*32 + kk];
  }
  #pragma unroll
  for (int ks = 0; ks < 4; ks++)
    #pragma unroll
    for (int i = 0; i < 8; i++) {
      const int kk = ks*32 + q*8 + i;
      whhR[ks][i] = (_Float16)W_hh[jR*128 + kk];
      whhZ[ks][i] = (_Float16)W_hh[jZ*128 + kk];
      whhN[ks][i] = (_Float16)W_hh[jN*128 + kk];
    }

  float hreg[4] = {0.f, 0.f, 0.f, 0.f};
  const f32x4 zero4 = {0.f, 0.f, 0.f, 0.f};
  f32x4 accPreR = zero4, accPreZ = zero4, accPreN = zero4;

  // RK4 lane mapping (tail waves 0,1): active lanes l<32; batch = (l>>2)+w*8
  const int s_ = l & 3;
  const int b4w = (l >> 2) + w*8;       // used only when w<2 && l<32
  const float jr0 = jmp[0*5 + s_], jr1 = jmp[1*5 + s_], jr2 = jmp[2*5 + s_];
  const float j40 = (s_==3) ? jmp[4]  : 0.f;
  const float j41 = (s_==3) ? jmp[9]  : 0.f;
  const float j42 = (s_==3) ? jmp[14] : 0.f;

  // u-prefetch mapping (wave2)
  const int upb = l/3, upc = l - (l/3)*3;             // l < 48

  __syncthreads();

  // hoist loop-invariant LDS biases into registers
  const float br  = sm.brz[jR];
  const float bz  = sm.brz[128 + jR];
  const float bx  = sm.bnx[jR];
  const float bn  = sm.bnh[jR];
  const float bb_ = sm.bhv[n16];

  #pragma unroll 1
  for (int k = 0; k < KTOT; k++) {
    const int buf  = k & 1;
    const int nbuf = (k + 1) & 1;
    const int kp   = (k + 1 < KTOT) ? (k + 1) : (KTOT - 1);

    // ---- phase LIFT: one silu(feat.Wl) value per thread ----
    {
      const f32x4 uu = *(const f32x4*)&sm.ust[buf][lb][0];
      const f32x4 ya = *(const f32x4*)&sm.yst[lb][0];
      const f32x4 yc = *(const f32x4*)&sm.yst[lb][4];
      const float a = blv
        + uu[0]*wlc[0] + uu[1]*wlc[1] + uu[2]*wlc[2]
        + ya[0]*wlc[3] + ya[1]*wlc[4] + ya[2]*wlc[5] + ya[3]*wlc[6]
        + yc[0]*wlc[7];
      sm.xls[lb][lo] = (_Float16)(a * sigm(a));
    }
    __syncthreads();

    // ---- phase GATE: x-part MFMAs + activations ----
    {
      const half8 xf = *(const half8*)&sm.xls[n16][q*8];
      const f32x4 accR  = __builtin_amdgcn_mfma_f32_16x16x32_f16(xf, wihR, accPreR, 0,0,0);
      const f32x4 accZ  = __builtin_amdgcn_mfma_f32_16x16x32_f16(xf, wihZ, accPreZ, 0,0,0);
      const f32x4 accXN = __builtin_amdgcn_mfma_f32_16x16x32_f16(xf, wihN, zero4,   0,0,0);
      #pragma unroll
      for (int rg = 0; rg < 4; rg++) {
        const float r  = sigm(accR[rg] + br);
        const float z  = sigm(accZ[rg] + bz);
        const float nn = tanhfast(accXN[rg] + bx + r*(accPreN[rg] + bn));
        const float ho = hreg[rg];
        const float hn = nn + z*(ho - nn);
        hreg[rg] = hn;
        sm.hf16[q*4 + rg][jR] = (_Float16)hn;
      }
    }
    __syncthreads();

    // ---- phase CD ----
    const int km = k & 15, hh = (k >> 4) & 1;
    float pref_u = 0.f, pref_dt = 0.f;
    if (w == 2 && l < 48)
      pref_u = u_seq[((size_t)(B0 + upb)*KTOT + kp)*3 + upc];
    if (w == 3 && l < 16)
      pref_dt = dt_sq[(size_t)(B0 + l)*KTOT + kp];

    half8 hfrag[4];
    #pragma unroll
    for (int ks = 0; ks < 4; ks++)
      hfrag[ks] = *(const half8*)&sm.hf16[n16][ks*32 + q*8];

    // -- tail part A (waves 0,1): head MFMA + theta -> thring (own half) --
    if (w < 2) {
      __builtin_amdgcn_s_setprio(1);
      f32x4 accHa = __builtin_amdgcn_mfma_f32_16x16x32_f16(hfrag[0], whf[0], zero4, 0,0,0);
      f32x4 accHb = __builtin_amdgcn_mfma_f32_16x16x32_f16(hfrag[2], whf[2], zero4, 0,0,0);
      accHa = __builtin_amdgcn_mfma_f32_16x16x32_f16(hfrag[1], whf[1], accHa, 0,0,0);
      accHb = __builtin_amdgcn_mfma_f32_16x16x32_f16(hfrag[3], whf[3], accHb, 0,0,0);
      const f32x4 accH = accHa + accHb;
      if ((q >> 1) == w) {                 // rows q*4+rg in [w*8, w*8+8)
        #pragma unroll
        for (int rg = 0; rg < 4; rg++) {
          const float sg  = sigm(accH[rg] + bb_);
          const float thv = (n16 < 8) ? (0.01f + 2.99f*sg) : (0.3f*sg);
          if (n16 < 13) sm.thring[hh][q*4 + rg][km][n16] = thv;
        }
      }
    }

    // -- h-GEMM for step k+1 (ALL waves; fills tail's thring write->read gap) --
    accPreR = zero4; accPreZ = zero4; accPreN = zero4;
    #pragma unroll
    for (int ks = 0; ks < 4; ks++) {
      accPreR = __builtin_amdgcn_mfma_f32_16x16x32_f16(hfrag[ks], whhR[ks], accPreR, 0,0,0);
      accPreZ = __builtin_amdgcn_mfma_f32_16x16x32_f16(hfrag[ks], whhZ[ks], accPreZ, 0,0,0);
      accPreN = __builtin_amdgcn_mfma_f32_16x16x32_f16(hfrag[ks], whhN[ks], accPreN, 0,0,0);
    }

    // -- tail part B (waves 0,1, lanes 0-31): RK4 for own 8 batches --
    if (w < 2) {
      if (l < 32) {
        const float* th = &sm.thring[hh][b4w][km][0];
        const float dt = sm.dtst[buf][b4w];
        const float h  = dt * 0.1f;
        const float thm = th[s_ ? (s_ - 1) : 0];
        const float Zl  = s_ ? h*thm : 0.f;
        const float krs = s_ ? th[3 + s_] : 0.f;
        const float Zd  = -h*(th[s_] + krs);
        const float Zur = h*th[4 + s_];
        const float Zu  = (s_ < 3) ? Zur : 0.f;
        const float Zu4 = (s_ == 3) ? Zur : 0.f;
        const float Z43 = h*th[3];
        const float Z44 = -h*th[7];
        const float c0 = th[8], c1 = th[9], c2 = th[10], c3 = th[11], c4 = th[12];
        float Xa[5], Xa4[5], Xb[5], Xb4[5];
        #pragma unroll
        for (int j = 0; j < 5; j++) {
          const float zr = (j == s_) ? Zd : ((j == s_ + 1) ? Zur : ((j + 1 == s_) ? Zl : 0.f));
          Xa[j] = ((j == s_) ? 1.f : 0.f) + 0.25f*zr;
        }
        Xa4[0] = 0.f; Xa4[1] = 0.f; Xa4[2] = 0.f;
        Xa4[3] = 0.25f*Z43; Xa4[4] = 1.f + 0.25f*Z44;
        MATMUL(Xb, Xb4, Xa, Xa4, (1.f/3.f));   // X2 = I + (Z/3) X1
        MATMUL(Xa, Xa4, Xb, Xb4, 0.5f);        // X3 = S = I + (Z/2) X2
        const float bv  = h*(Xa[0]*c0 + Xa[1]*c1 + Xa[2]*c2 + Xa[3]*c3 + Xa[4]*c4);
        const float bv4 = h*(Xa4[0]*c0 + Xa4[1]*c1 + Xa4[2]*c2 + Xa4[3]*c3 + Xa4[4]*c4);
        MATMUL(Xb, Xb4, Xa, Xa4, 1.f);         // A = I + Z S
        const float uu0 = sm.ust[buf][b4w][0], uu1 = sm.ust[buf][b4w][1], uu2 = sm.ust[buf][b4w][2];
        float y  = sm.yst[b4w][s_] + uu0*jr0 + uu1*jr1 + uu2*jr2;
        float y4 = sm.yst[b4w][4]  + uu0*j40 + uu1*j41 + uu2*j42;
        #pragma unroll
        for (int ss = 0; ss < 10; ss++) {
          const float v0 = dppf<QB0>(y), v1 = dppf<QB1>(y),
                      v2 = dppf<QB2>(y), v3 = dppf<QB3>(y);
          const float v4 = dppf<QB3>(y4);
          const float a1 = fmaf(Xb[0],  v0, bv);
          const float a2 = fmaf(Xb[2],  v2, Xb[1]*v1);
          const float a3 = fmaf(Xb[4],  v4, Xb[3]*v3);
          const float b1 = fmaf(Xb4[0], v0, bv4);
          const float b2 = fmaf(Xb4[2], v2, Xb4[1]*v1);
          const float b3 = fmaf(Xb4[4], v4, Xb4[3]*v3);
          y  = fmaxf(a1 + (a2 + a3), 0.f);
          y4 = fmaxf(b1 + (b2 + b3), 0.f);
        }
        sm.yst[b4w][s_] = y;
        sm.yring[hh][b4w][km][s_] = y;
        if (s_ == 3) { sm.yst[b4w][4] = y4; sm.yring[hh][b4w][km][4] = y4; }
      }
      __builtin_amdgcn_s_setprio(0);
    } else if (w >= 4) {
      // ---- ring flush: steps k-16..k-1, coalesced f32x4, waves 4-7 ----
      if ((k & 15) == 0 && k >= 16) {
        const int hf = hh ^ 1;
        const int kb = k - 16;
        const int idx = t - 256;                 // 0..255
        #pragma unroll
        for (int rep = 0; rep < 5; rep++) {
          const int o = idx + rep*256;
          if (o < 1152) {
            if (o < 320) {
              const int b = o/20, j = o - (o/20)*20;
              *(f32x4*)&y_out[((size_t)(B0 + b)*KTOT + kb)*5 + j*4] =
                  *(const f32x4*)((const float*)&sm.yring[hf][b][0][0] + j*4);
            } else {
              const int o2 = o - 320;
              const int b = o2/52, j = o2 - (o2/52)*52;
              *(f32x4*)&th_out[((size_t)(B0 + b)*KTOT + kb)*13 + j*4] =
                  *(const f32x4*)((const float*)&sm.thring[hf][b][0][0] + j*4);
            }
          }
        }
      }
    }
    // land prefetch into LDS
    if (w == 2 && l < 48) sm.ust[nbuf][upb][upc] = pref_u;
    if (w == 3 && l < 16) sm.dtst[nbuf][l] = pref_dt;
    __syncthreads();
  }

  // epilogue: flush the last 16 steps (steps 496..511, half index 1)
  {
    const int kb = KTOT - 16;
    const int hf = 1;
    #pragma unroll
    for (int rep = 0; rep < 3; rep++) {
      const int o = t + rep*512;
      if (o < 1152) {
        if (o < 320) {
          const int b = o/20, j = o - (o/20)*20;
          *(f32x4*)&y_out[((size_t)(B0 + b)*KTOT + kb)*5 + j*4] =
              *(const f32x4*)((const float*)&sm.yring[hf][b][0][0] + j*4);
        } else {
          const int o2 = o - 320;
          const int b = o2/52, j = o2 - (o2/52)*52;
          *(f32x4*)&th_out[((size_t)(B0 + b)*KTOT + kb)*13 + j*4] =
              *(const f32x4*)((const float*)&sm.thring[hf][b][0][0] + j*4);
        }
      }
    }
  }
}

extern "C" void kernel_launch(void* const* d_in, const int* in_sizes, int n_in,
                              void* d_out, int out_size, void* d_ws, size_t ws_size,
                              hipStream_t stream) {
  const float* y0     = (const float*)d_in[0];
  const float* u_seq  = (const float*)d_in[1];
  const float* dt_sq  = (const float*)d_in[2];
  const float* Wl     = (const float*)d_in[3];
  const float* bl     = (const float*)d_in[4];
  const float* W_ih   = (const float*)d_in[5];
  const float* b_ih   = (const float*)d_in[6];
  const float* W_hh   = (const float*)d_in[7];
  const float* b_hh   = (const float*)d_in[8];
  const float* Wh     = (const float*)d_in[9];
  const float* bh     = (const float*)d_in[10];
  const float* jmp    = (const float*)d_in[11];
  float* y_out  = (float*)d_out;
  float* th_out = y_out + (size_t)4096 * KTOT * 5;   // y (B,K,5) then theta (B,K,13)
  rnn_scan_kernel<<<256, 512, 0, stream>>>(
      y0, u_seq, dt_sq, Wl, bl, W_ih, b_ih, W_hh, b_hh, Wh, bh, jmp, y_out, th_out);
}

// Round 11
// 1414.877 us; speedup vs baseline: 1.0200x; 1.0081x over previous
//
#include <hip/hip_runtime.h>
#include <cstdint>
#include <cstddef>

// SimpleRNN: B=4096, K=512, U=3, P=5, LIFT=32, HID=128, NSUB=10
// Round 14: resubmission of round-13 (infra failure; rounds 1/4/7/10 all infra,
// all passed on unchanged resubmit). Base = round 6 (1310 us best) plus:
//  - Swapped head MFMA: mfma(whf, hfrag) -> C holds theta[n=4q+rg][batch=n16].
//    Theta reaches RK4 lanes via 13 ds_bpermute (in-register transpose) +
//    static selects instead of the thring LDS write->wait->read round trip.
//  - thring ring write moved AFTER RK4 (consumers are 16 steps later).
//  - dt/u reads hoisted to tail start (hide under head MFMA).
//  - head MFMA chain 2+2 instead of 4-deep.

#define KTOT 512
#define BB   16

typedef _Float16 half8 __attribute__((ext_vector_type(8)));
typedef float    f32x4 __attribute__((ext_vector_type(4)));

struct __align__(16) Smem {
  _Float16 hf16[BB][136];        // f16 hidden (A-frag source)       4352 B
  _Float16 xls[BB][32];          // f16 lift output (A-frag source)  1024 B
  float yring[2][BB][16][5];     // output ring                     10240 B
  float thring[2][BB][16][13];   // theta ring                      26624 B
  float brz[256];
  float bnx[128];
  float bnh[128];
  float bhv[16];
  float yst[BB][8];
  float ust[2][BB][4];           // double-buffered u
  float dtst[2][BB];             // double-buffered dt
};

__device__ __forceinline__ float sigm(float x)     { return 1.f / (1.f + __expf(-x)); }
__device__ __forceinline__ float tanhfast(float x) { return 1.f - 2.f / (1.f + __expf(2.f * x)); }

template<int CTRL>
__device__ __forceinline__ float dppf(float x) {
  return __int_as_float(__builtin_amdgcn_mov_dpp(__float_as_int(x), CTRL, 0xf, 0xf, true));
}
__device__ __forceinline__ float bpermf(int byteidx, float v) {
  return __int_as_float(__builtin_amdgcn_ds_bpermute(byteidx, __float_as_int(v)));
}
#define QP_PLUS  0x39   // quad_perm [1,2,3,0]
#define QP_MINUS 0x93   // quad_perm [3,0,1,2]
#define QB0 0x00
#define QB1 0x55
#define QB2 0xAA
#define QB3 0xFF

// Y = I + ALPHA * Z * X   (row-per-lane; lane3 also owns row4 in X4r/Y4r)
#define MATMUL(Yr, Y4r, Xr, X4r, ALPHA) do {                                  \
  float xm_[5], xp_[5];                                                       \
  _Pragma("unroll")                                                           \
  for (int j_ = 0; j_ < 5; j_++) {                                            \
    xm_[j_] = dppf<QP_MINUS>(Xr[j_]);                                         \
    xp_[j_] = dppf<QP_PLUS >(Xr[j_]);                                         \
  }                                                                           \
  _Pragma("unroll")                                                           \
  for (int j_ = 0; j_ < 5; j_++) {                                            \
    const float ac_ = Zl*xm_[j_] + Zd*Xr[j_] + Zu*xp_[j_] + Zu4*X4r[j_];      \
    const float a4_ = Z43*Xr[j_] + Z44*X4r[j_];                               \
    Yr[j_]  = ((j_ == s_) ? 1.f : 0.f) + (ALPHA)*ac_;                         \
    Y4r[j_] = ((j_ == 4 ) ? 1.f : 0.f) + (ALPHA)*a4_;                         \
  } } while (0)

__global__ __launch_bounds__(512, 2) void rnn_scan_kernel(
    const float* __restrict__ y0,    const float* __restrict__ u_seq,
    const float* __restrict__ dt_sq, const float* __restrict__ Wl,
    const float* __restrict__ bl,    const float* __restrict__ W_ih,
    const float* __restrict__ b_ih,  const float* __restrict__ W_hh,
    const float* __restrict__ b_hh,  const float* __restrict__ Wh,
    const float* __restrict__ bh,    const float* __restrict__ jmp,
    float* __restrict__ y_out, float* __restrict__ th_out)
{
  __shared__ Smem sm;
  const int t   = threadIdx.x;
  const int w   = t >> 6;          // 0..7
  const int l   = t & 63;
  const int n16 = l & 15;
  const int q   = l >> 4;
  const int B0  = blockIdx.x * BB;

  // ---------------- one-time init ----------------
  if (t < 256) sm.brz[t] = b_ih[t] + b_hh[t];
  if (t < 128) { sm.bnx[t] = b_ih[256+t]; sm.bnh[t] = b_hh[256+t]; }
  if (t < 16)  sm.bhv[t] = (t < 13) ? bh[t] : 0.f;
  if (t >= 256 && t < 384) { const int b = (t-256) >> 3, i = (t-256) & 7;
    sm.yst[b][i] = (i < 5) ? (y0[(size_t)(B0+b)*5 + i] + 0.01f) : 0.f; }
  if (t >= 384 && t < 432) { const int idx = t-384, b = idx/3, c = idx - (idx/3)*3;
    sm.ust[0][b][c] = u_seq[((size_t)(B0+b)*KTOT + 0)*3 + c]; }
  if (t >= 432 && t < 448) sm.dtst[0][t-432] = dt_sq[(size_t)(B0+(t-432))*KTOT + 0];

  // lift: one output per thread; Wl column pinned in VGPRs (loop-invariant)
  const int lb = t >> 5;           // batch 0..15
  const int lo = t & 31;           // lift out col 0..31
  float wlc[8];
  #pragma unroll
  for (int c = 0; c < 8; c++) wlc[c] = Wl[lo*8 + c];
  const float blv = bl[lo];

  // head A-frags (swapped-operand use: A rows = theta index n)
  half8 whf[4];
  #pragma unroll
  for (int ks = 0; ks < 4; ks++)
    #pragma unroll
    for (int i = 0; i < 8; i++) {
      const int kk = ks*32 + q*8 + i;
      whf[ks][i] = (n16 < 13) ? (_Float16)Wh[n16*128 + kk] : (_Float16)0.f;
    }

  // GRU weight fragments: this wave's single 16-col slice
  const int jR = w*16 + n16;
  const int jZ = jR + 128, jN = jR + 256;
  half8 wihR, wihZ, wihN, whhR[4], whhZ[4], whhN[4];
  #pragma unroll
  for (int i = 0; i < 8; i++) {
    const int kk = q*8 + i;
    wihR[i] = (_Float16)W_ih[jR*32 + kk];
    wihZ[i] = (_Float16)W_ih[jZ*32 + kk];
    wihN[i] = (_Float16)W_ih[jN*32 + kk];
  }
  #pragma unroll
  for (int ks = 0; ks < 4; ks++)
    #pragma unroll
    for (int i = 0; i < 8; i++) {
      const int kk = ks*32 + q*8 + i;
      whhR[ks][i] = (_Float16)W_hh[jR*128 + kk];
      whhZ[ks][i] = (_Float16)W_hh[jZ*128 + kk];
      whhN[ks][i] = (_Float16)W_hh[jN*128 + kk];
    }

  float hreg[4] = {0.f, 0.f, 0.f, 0.f};
  const f32x4 zero4 = {0.f, 0.f, 0.f, 0.f};
  f32x4 accPreR = zero4, accPreZ = zero4, accPreN = zero4;

  // RK4 lane mapping (wave0): lane = b4*4 + s_, row4 state on s_==3
  const int s_ = l & 3, b4 = l >> 2;
  const float jr0 = jmp[0*5 + s_], jr1 = jmp[1*5 + s_], jr2 = jmp[2*5 + s_];
  const float j40 = (s_==3) ? jmp[4]  : 0.f;
  const float j41 = (s_==3) ? jmp[9]  : 0.f;
  const float j42 = (s_==3) ? jmp[14] : 0.f;
  // bpermute byte-indices for theta transpose: src lane = 16*qp + b4
  const int bpi0 = (b4      ) << 2;
  const int bpi1 = (b4 + 16 ) << 2;
  const int bpi2 = (b4 + 32 ) << 2;
  const int bpi3 = (b4 + 48 ) << 2;

  // u-prefetch mapping (wave1)
  const int upb = l/3, upc = l - (l/3)*3;             // l < 48

  __syncthreads();

  // hoist loop-invariant LDS biases into registers
  const float br  = sm.brz[jR];
  const float bz  = sm.brz[128 + jR];
  const float bx  = sm.bnx[jR];
  const float bn  = sm.bnh[jR];
  const f32x4 bhv4 = *(const f32x4*)&sm.bhv[q*4];   // head bias per ROW n=4q+rg

  #pragma unroll 1
  for (int k = 0; k < KTOT; k++) {
    const int buf  = k & 1;
    const int nbuf = (k + 1) & 1;
    const int kp   = (k + 1 < KTOT) ? (k + 1) : (KTOT - 1);

    // ---- phase LIFT: one silu(feat.Wl) value per thread ----
    {
      const f32x4 uu = *(const f32x4*)&sm.ust[buf][lb][0];
      const f32x4 ya = *(const f32x4*)&sm.yst[lb][0];
      const f32x4 yc = *(const f32x4*)&sm.yst[lb][4];
      const float a = blv
        + uu[0]*wlc[0] + uu[1]*wlc[1] + uu[2]*wlc[2]
        + ya[0]*wlc[3] + ya[1]*wlc[4] + ya[2]*wlc[5] + ya[3]*wlc[6]
        + yc[0]*wlc[7];
      sm.xls[lb][lo] = (_Float16)(a * sigm(a));
    }
    __syncthreads();

    // ---- phase GATE: x-part MFMAs + activations ----
    {
      const half8 xf = *(const half8*)&sm.xls[n16][q*8];
      const f32x4 accR  = __builtin_amdgcn_mfma_f32_16x16x32_f16(xf, wihR, accPreR, 0,0,0);
      const f32x4 accZ  = __builtin_amdgcn_mfma_f32_16x16x32_f16(xf, wihZ, accPreZ, 0,0,0);
      const f32x4 accXN = __builtin_amdgcn_mfma_f32_16x16x32_f16(xf, wihN, zero4,   0,0,0);
      #pragma unroll
      for (int rg = 0; rg < 4; rg++) {
        const float r  = sigm(accR[rg] + br);
        const float z  = sigm(accZ[rg] + bz);
        const float nn = tanhfast(accXN[rg] + bx + r*(accPreN[rg] + bn));
        const float ho = hreg[rg];
        const float hn = nn + z*(ho - nn);
        hreg[rg] = hn;
        sm.hf16[q*4 + rg][jR] = (_Float16)hn;
      }
    }
    __syncthreads();

    // ---- phase CD: h-GEMM(k+1) || wave0: head+theta+RK4 || w4-7: flush ----
    const int km = k & 15, hh = (k >> 4) & 1;
    float pref_u = 0.f, pref_dt = 0.f;
    if (w == 1 && l < 48)
      pref_u = u_seq[((size_t)(B0 + upb)*KTOT + kp)*3 + upc];
    if (w == 2 && l < 16)
      pref_dt = dt_sq[(size_t)(B0 + l)*KTOT + kp];

    half8 hfrag[4];
    #pragma unroll
    for (int ks = 0; ks < 4; ks++)
      hfrag[ks] = *(const half8*)&sm.hf16[n16][ks*32 + q*8];

    accPreR = zero4; accPreZ = zero4; accPreN = zero4;
    #pragma unroll
    for (int ks = 0; ks < 4; ks++) {
      accPreR = __builtin_amdgcn_mfma_f32_16x16x32_f16(hfrag[ks], whhR[ks], accPreR, 0,0,0);
      accPreZ = __builtin_amdgcn_mfma_f32_16x16x32_f16(hfrag[ks], whhZ[ks], accPreZ, 0,0,0);
      accPreN = __builtin_amdgcn_mfma_f32_16x16x32_f16(hfrag[ks], whhN[ks], accPreN, 0,0,0);
    }

    if (w == 0) {
      // issue dt/u reads early (hide LDS latency under head MFMAs)
      const float dt  = sm.dtst[buf][b4];
      const float uu0 = sm.ust[buf][b4][0], uu1 = sm.ust[buf][b4][1], uu2 = sm.ust[buf][b4][2];
      // head -> theta, SWAPPED operands: C = theta[n=4q+rg][batch=n16]
      f32x4 accHa = __builtin_amdgcn_mfma_f32_16x16x32_f16(whf[0], hfrag[0], zero4, 0,0,0);
      f32x4 accHb = __builtin_amdgcn_mfma_f32_16x16x32_f16(whf[2], hfrag[2], zero4, 0,0,0);
      accHa = __builtin_amdgcn_mfma_f32_16x16x32_f16(whf[1], hfrag[1], accHa, 0,0,0);
      accHb = __builtin_amdgcn_mfma_f32_16x16x32_f16(whf[3], hfrag[3], accHb, 0,0,0);
      const f32x4 accH = accHa + accHb;
      f32x4 tv;
      #pragma unroll
      for (int rg = 0; rg < 4; rg++) {
        const float sg = sigm(accH[rg] + bhv4[rg]);
        tv[rg] = (q < 2) ? (0.01f + 2.99f*sg) : (0.3f*sg);   // n=4q+rg<8 <=> q<2
      }
      // in-register theta transpose: p_n = theta[n][b4] via 13 bpermutes
      const float p0  = bpermf(bpi0, tv[0]);
      const float p1  = bpermf(bpi0, tv[1]);
      const float p2  = bpermf(bpi0, tv[2]);
      const float p3  = bpermf(bpi0, tv[3]);
      const float p4  = bpermf(bpi1, tv[0]);
      const float p5  = bpermf(bpi1, tv[1]);
      const float p6  = bpermf(bpi1, tv[2]);
      const float p7  = bpermf(bpi1, tv[3]);
      const float p8  = bpermf(bpi2, tv[0]);
      const float p9  = bpermf(bpi2, tv[1]);
      const float p10 = bpermf(bpi2, tv[2]);
      const float p11 = bpermf(bpi2, tv[3]);
      const float p12 = bpermf(bpi3, tv[0]);
      // s_-dependent selects (static register access, rule #20)
      const bool sB0 = (s_ == 0), sB1 = (s_ == 1), sB2 = (s_ == 2);
      const float thm  = sB0 ? p0 : (sB1 ? p0 : (sB2 ? p1 : p2));  // th[s_?s_-1:0]
      const float ths  = sB0 ? p0 : (sB1 ? p1 : (sB2 ? p2 : p3));  // th[s_]
      const float krsv = sB0 ? p3 : (sB1 ? p4 : (sB2 ? p5 : p6));  // th[3+s_]
      const float Zurv = sB0 ? p4 : (sB1 ? p5 : (sB2 ? p6 : p7));  // th[4+s_]
      // ---- exact-linear RK4 ----
      const float h   = dt * 0.1f;
      const float Zl  = s_ ? h*thm : 0.f;
      const float krs = s_ ? krsv : 0.f;
      const float Zd  = -h*(ths + krs);
      const float Zur = h*Zurv;
      const float Zu  = (s_ < 3) ? Zur : 0.f;
      const float Zu4 = (s_ == 3) ? Zur : 0.f;
      const float Z43 = h*p3;
      const float Z44 = -h*p7;
      const float c0 = p8, c1 = p9, c2 = p10, c3 = p11, c4 = p12;
      float Xa[5], Xa4[5], Xb[5], Xb4[5];
      #pragma unroll
      for (int j = 0; j < 5; j++) {
        const float zr = (j == s_) ? Zd : ((j == s_ + 1) ? Zur : ((j + 1 == s_) ? Zl : 0.f));
        Xa[j] = ((j == s_) ? 1.f : 0.f) + 0.25f*zr;
      }
      Xa4[0] = 0.f; Xa4[1] = 0.f; Xa4[2] = 0.f;
      Xa4[3] = 0.25f*Z43; Xa4[4] = 1.f + 0.25f*Z44;
      MATMUL(Xb, Xb4, Xa, Xa4, (1.f/3.f));   // X2 = I + (Z/3) X1
      MATMUL(Xa, Xa4, Xb, Xb4, 0.5f);        // X3 = S = I + (Z/2) X2
      const float bv  = h*(Xa[0]*c0 + Xa[1]*c1 + Xa[2]*c2 + Xa[3]*c3 + Xa[4]*c4);
      const float bv4 = h*(Xa4[0]*c0 + Xa4[1]*c1 + Xa4[2]*c2 + Xa4[3]*c3 + Xa4[4]*c4);
      MATMUL(Xb, Xb4, Xa, Xa4, 1.f);         // A = I + Z S
      float y  = sm.yst[b4][s_] + uu0*jr0 + uu1*jr1 + uu2*jr2;
      float y4 = sm.yst[b4][4]  + uu0*j40 + uu1*j41 + uu2*j42;
      #pragma unroll
      for (int ss = 0; ss < 10; ss++) {
        const float v0 = dppf<QB0>(y), v1 = dppf<QB1>(y),
                    v2 = dppf<QB2>(y), v3 = dppf<QB3>(y);
        const float v4 = dppf<QB3>(y4);
        const float a1 = fmaf(Xb[0],  v0, bv);
        const float a2 = fmaf(Xb[2],  v2, Xb[1]*v1);
        const float a3 = fmaf(Xb[4],  v4, Xb[3]*v3);
        const float b1 = fmaf(Xb4[0], v0, bv4);
        const float b2 = fmaf(Xb4[2], v2, Xb4[1]*v1);
        const float b3 = fmaf(Xb4[4], v4, Xb4[3]*v3);
        y  = fmaxf(a1 + (a2 + a3), 0.f);
        y4 = fmaxf(b1 + (b2 + b3), 0.f);
      }
      sm.yst[b4][s_] = y;
      sm.yring[hh][b4][km][s_] = y;
      if (s_ == 3) { sm.yst[b4][4] = y4; sm.yring[hh][b4][km][4] = y4; }
      // theta ring write (off critical path; consumers flush 16 steps later)
      #pragma unroll
      for (int rg = 0; rg < 4; rg++)
        if (q*4 + rg < 13) sm.thring[hh][n16][km][q*4 + rg] = tv[rg];
    } else if (w >= 4) {
      // ---- ring flush: steps k-16..k-1, coalesced f32x4, waves 4-7 ----
      if ((k & 15) == 0 && k >= 16) {
        const int hf = hh ^ 1;
        const int kb = k - 16;
        const int idx = t - 256;                 // 0..255
        #pragma unroll
        for (int rep = 0; rep < 5; rep++) {
          const int o = idx + rep*256;
          if (o < 1152) {
            if (o < 320) {
              const int b = o/20, j = o - (o/20)*20;
              *(f32x4*)&y_out[((size_t)(B0 + b)*KTOT + kb)*5 + j*4] =
                  *(const f32x4*)((const float*)&sm.yring[hf][b][0][0] + j*4);
            } else {
              const int o2 = o - 320;
              const int b = o2/52, j = o2 - (o2/52)*52;
              *(f32x4*)&th_out[((size_t)(B0 + b)*KTOT + kb)*13 + j*4] =
                  *(const f32x4*)((const float*)&sm.thring[hf][b][0][0] + j*4);
            }
          }
        }
      }
    }
    // land prefetch into LDS (loads have had the whole phase to complete)
    if (w == 1 && l < 48) sm.ust[nbuf][upb][upc] = pref_u;
    if (w == 2 && l < 16) sm.dtst[nbuf][l] = pref_dt;
    __syncthreads();
  }

  // epilogue: flush the last 16 steps (steps 496..511, half index 1)
  {
    const int kb = KTOT - 16;
    const int hf = 1;
    #pragma unroll
    for (int rep = 0; rep < 3; rep++) {
      const int o = t + rep*512;
      if (o < 1152) {
        if (o < 320) {
          const int b = o/20, j = o - (o/20)*20;
          *(f32x4*)&y_out[((size_t)(B0 + b)*KTOT + kb)*5 + j*4] =
              *(const f32x4*)((const float*)&sm.yring[hf][b][0][0] + j*4);
        } else {
          const int o2 = o - 320;
          const int b = o2/52, j = o2 - (o2/52)*52;
          *(f32x4*)&th_out[((size_t)(B0 + b)*KTOT + kb)*13 + j*4] =
              *(const f32x4*)((const float*)&sm.thring[hf][b][0][0] + j*4);
        }
      }
    }
  }
}

extern "C" void kernel_launch(void* const* d_in, const int* in_sizes, int n_in,
                              void* d_out, int out_size, void* d_ws, size_t ws_size,
                              hipStream_t stream) {
  const float* y0     = (const float*)d_in[0];
  const float* u_seq  = (const float*)d_in[1];
  const float* dt_sq  = (const float*)d_in[2];
  const float* Wl     = (const float*)d_in[3];
  const float* bl     = (const float*)d_in[4];
  const float* W_ih   = (const float*)d_in[5];
  const float* b_ih   = (const float*)d_in[6];
  const float* W_hh   = (const float*)d_in[7];
  const float* b_hh   = (const float*)d_in[8];
  const float* Wh     = (const float*)d_in[9];
  const float* bh     = (const float*)d_in[10];
  const float* jmp    = (const float*)d_in[11];
  float* y_out  = (float*)d_out;
  float* th_out = y_out + (size_t)4096 * KTOT * 5;   // y (B,K,5) then theta (B,K,13)
  rnn_scan_kernel<<<256, 512, 0, stream>>>(
      y0, u_seq, dt_sq, Wl, bl, W_ih, b_ih, W_hh, b_hh, Wh, bh, jmp, y_out, th_out);
}